// Round 10
// baseline (473.671 us; speedup 1.0000x reference)
//
#include <hip/hip_runtime.h>
#include <math.h>

// Problem constants
#define BB 8
#define CC 64
#define TT 512
#define FF 256

typedef float floatx4 __attribute__((ext_vector_type(4)));

constexpr int TOFF = BB * FF;                       // 2048
constexpr int COFF = BB * FF + BB * TT;             // 6144
constexpr int NSUM = BB * FF + BB * TT + BB * CC;   // 6656 floats

// ws layout (floats)
constexpr long PF_OFF = 0;                          // Pfreq [4096][256]
constexpr long PT_OFF = PF_OFF + 4096L * 256;       // Ptime [4096][64]
constexpr long PC_OFF = PT_OFF + 4096L * 64;        // Pch   [4096]
constexpr long G_OFF  = PC_OFF + 4096;              // gates [NSUM]
constexpr long FL_OFF = G_OFF + NSUM;               // flag  (1 int)

// ---------------------------------------------------------------------------
// Kernel 1: pool (R7-verified). One contiguous 64KB chunk per block,
// register-only inner loop, one-time cross-lane epilogue, plain-store
// partials. Temporal loads keep x resident in L3 (R6: apply ~94% L3 hits).
// Also zeroes the gate-ready flag for kernel 2 (runs strictly before it).
// ---------------------------------------------------------------------------
__global__ __launch_bounds__(256) void pool_k(const float* __restrict__ x,
                                              float* __restrict__ pf,
                                              float* __restrict__ pt,
                                              float* __restrict__ pc,
                                              int* __restrict__ flag) {
    __shared__ float tr[16][257];
    __shared__ float fr[256];
    __shared__ float cw[4];
    const int tid  = threadIdx.x;
    const int lane = tid & 63;
    const int wid  = tid >> 6;
    const int chunk = blockIdx.x;                    // 0..4095

    if (chunk == 0 && tid == 0) *flag = 0;           // reset for kernel 2

    const floatx4* __restrict__ x4 = (const floatx4*)x;
    const long base = (long)chunk * 4096 + wid * 1024 + lane;

    float a0 = 0.f, a1 = 0.f, a2 = 0.f, a3 = 0.f;    // freq partials
    float ach[16];                                   // row sums (time)
    #pragma unroll
    for (int k = 0; k < 16; ++k) {
        floatx4 d = x4[base + k * 64];               // temporal: fill L3
        a0 += d.x; a1 += d.y; a2 += d.z; a3 += d.w;
        ach[k] = (d.x + d.y) + (d.z + d.w);
    }
    float csum = 0.f;
    #pragma unroll
    for (int k = 0; k < 16; ++k) csum += ach[k];
    #pragma unroll
    for (int o = 32; o > 0; o >>= 1) csum += __shfl_xor(csum, o, 64);

    fr[tid] = 0.f;
    #pragma unroll
    for (int k = 0; k < 16; ++k) tr[k][tid] = ach[k];
    if (lane == 0) cw[wid] = csum;
    __syncthreads();

    atomicAdd(&fr[4 * lane + 0], a0);
    atomicAdd(&fr[4 * lane + 1], a1);
    atomicAdd(&fr[4 * lane + 2], a2);
    atomicAdd(&fr[4 * lane + 3], a3);

    {   // time: row s of chunk summed by 4 threads (q), then 2 shuffles
        const int s = tid >> 2, q = tid & 3;
        float v = 0.f;
        #pragma unroll
        for (int j = 0; j < 16; ++j)
            v += tr[s & 15][(s >> 4) * 64 + q * 16 + j];
        v += __shfl_xor(v, 1, 64);
        v += __shfl_xor(v, 2, 64);
        if (q == 0) pt[chunk * 64 + s] = v;
    }
    __syncthreads();

    pf[chunk * 256 + tid] = fr[tid];
    if (tid == 0) pc[chunk] = (cw[0] + cw[1]) + (cw[2] + cw[3]);
}

// ---------------------------------------------------------------------------
// Kernel 2: gate_apply. Blocks 0..23: compute one (g,b) gate unit (R7's
// proven 512-thread gate body), release flag. Blocks 24..1047: prefetch 4
// x-float4 (x is pure input -> safe before gates), spin on flag (producers
// never wait -> deadlock-free), then apply descending with nt stores.
// ---------------------------------------------------------------------------
__global__ __launch_bounds__(512) void gate_apply_k(
    const float* __restrict__ x,
    const float* __restrict__ w1f, const float* __restrict__ w2f,
    const float* __restrict__ w1t, const float* __restrict__ w2t,
    const float* __restrict__ w1c, const float* __restrict__ w2c,
    const float* __restrict__ pf, const float* __restrict__ pt,
    const float* __restrict__ pc, float* __restrict__ gates,
    int* __restrict__ flag, float* __restrict__ out) {
    __shared__ __align__(16) float s[512];
    __shared__ __align__(16) float h[512];
    const int tid = threadIdx.x;
    const int bid = blockIdx.x;

    if (bid < 24) {
        // ---------------- gate unit (g,b) ----------------
        const int g = bid >> 3;
        const int b = bid & 7;
        int dim; const float *w1, *w2; float* gout; float inv;
        if (g == 0) { dim = FF; w1 = w1f; w2 = w2f; gout = gates + b * FF;
                      inv = 1.f / (float)(CC * TT); }
        else if (g == 1) { dim = TT; w1 = w1t; w2 = w2t;
                      gout = gates + TOFF + b * TT;
                      inv = 1.f / (float)(CC * FF); }
        else { dim = CC; w1 = w1c; w2 = w2c; gout = gates + COFF + b * CC;
                      inv = 1.f / (float)(TT * FF); }

        if (g == 0) {
            const int f = tid & 255, half = tid >> 8;
            float acc = 0.f;
            const float* __restrict__ p =
                pf + ((long)(b * 512 + half * 256) * 256) + f;
            #pragma unroll 8
            for (int ch = 0; ch < 256; ++ch) acc += p[(long)ch * 256];
            h[tid] = acc;
            __syncthreads();
            if (tid < 256) s[tid] = (h[tid] + h[tid + 256]) * inv;
        } else if (g == 1) {
            float acc = 0.f;
            const float* __restrict__ p =
                pt + ((long)(b * 512 + (tid >> 6)) * 64) + (tid & 63);
            #pragma unroll 8
            for (int c = 0; c < 64; ++c) acc += p[(long)c * 8 * 64];
            s[tid] = acc * inv;
        } else {
            if (tid < CC) {
                float acc = 0.f;
                #pragma unroll
                for (int j = 0; j < 8; ++j) acc += pc[b * 512 + tid * 8 + j];
                s[tid] = acc * inv;
            }
        }
        __syncthreads();

        for (int row = tid; row < dim; row += 512) {   // layer 1: relu
            const floatx4* __restrict__ wr = (const floatx4*)(w1 + (long)row * dim);
            const floatx4* __restrict__ sv = (const floatx4*)s;
            float c0 = 0.f, c1 = 0.f, c2 = 0.f, c3 = 0.f;
            for (int j = 0; j < dim / 4; ++j) {
                floatx4 w = wr[j]; floatx4 sj = sv[j];
                c0 += w.x * sj.x; c1 += w.y * sj.y;
                c2 += w.z * sj.z; c3 += w.w * sj.w;
            }
            h[row] = fmaxf((c0 + c1) + (c2 + c3), 0.f);
        }
        __syncthreads();
        for (int row = tid; row < dim; row += 512) {   // layer 2: sigmoid
            const floatx4* __restrict__ wr = (const floatx4*)(w2 + (long)row * dim);
            const floatx4* __restrict__ hv = (const floatx4*)h;
            float c0 = 0.f, c1 = 0.f, c2 = 0.f, c3 = 0.f;
            for (int j = 0; j < dim / 4; ++j) {
                floatx4 w = wr[j]; floatx4 hj = hv[j];
                c0 += w.x * hj.x; c1 += w.y * hj.y;
                c2 += w.z * hj.z; c3 += w.w * hj.w;
            }
            gout[row] = 1.f / (1.f + expf(-((c0 + c1) + (c2 + c3))));
        }
        __syncthreads();
        if (tid == 0) {
            __threadfence();                 // release gates
            atomicAdd(flag, 1);
        }
        return;                              // gate blocks do no apply work
    }

    // ---------------- apply (blocks 24..1047) ----------------
    const floatx4* __restrict__ x4 = (const floatx4*)x;
    floatx4* __restrict__ o4 = (floatx4*)out;
    const long base3 = (long)(bid - 24) * 512 + tid;   // < 2^19
    const int f4 = (int)(base3 & 63);
    const int t  = (int)((base3 >> 6) & (TT - 1));
    const int cb = (int)((base3 >> 15) & (CC - 1));

    // prefetch k=31..28 (x is input-only: safe before gates are ready)
    floatx4 pre[4];
    #pragma unroll
    for (int i = 0; i < 4; ++i)
        pre[i] = x4[base3 + ((long)(31 - i) << 19)];

    if (tid == 0) {                          // one thread spins; rest wait
        while (__hip_atomic_load(flag, __ATOMIC_ACQUIRE,
                                 __HIP_MEMORY_SCOPE_AGENT) < 24)
            __builtin_amdgcn_s_sleep(10);
        __threadfence();
    }
    __syncthreads();

    const float* __restrict__ gts = gates;
    #pragma unroll
    for (int k = 31; k >= 28; --k) {         // use prefetched registers
        const int b = k >> 2;
        const int c = (cb + k * 16) & (CC - 1);
        const floatx4 fm = ((const floatx4*)(gts + b * FF))[f4];
        const float gadd = gts[TOFF + b * TT + t]
                         + gts[COFF + b * CC + c] + 1.0f;
        floatx4 o = pre[31 - k] * (fm + gadd);
        __builtin_nontemporal_store(o, &o4[base3 + ((long)k << 19)]);
    }
    #pragma unroll 4
    for (int k = 27; k >= 0; --k) {          // descending: chase L3 MRU
        const int b = k >> 2;
        const int c = (cb + k * 16) & (CC - 1);
        const floatx4 fm = ((const floatx4*)(gts + b * FF))[f4];
        const float gadd = gts[TOFF + b * TT + t]
                         + gts[COFF + b * CC + c] + 1.0f;
        const long v = base3 + ((long)k << 19);
        floatx4 d = x4[v];                   // mostly L3 hits
        floatx4 o = d * (fm + gadd);
        __builtin_nontemporal_store(o, &o4[v]);
    }
}

extern "C" void kernel_launch(void* const* d_in, const int* in_sizes, int n_in,
                              void* d_out, int out_size, void* d_ws, size_t ws_size,
                              hipStream_t stream) {
    const float* x   = (const float*)d_in[0];
    const float* w1f = (const float*)d_in[1];
    const float* w2f = (const float*)d_in[2];
    const float* w1t = (const float*)d_in[3];
    const float* w2t = (const float*)d_in[4];
    const float* w1c = (const float*)d_in[5];
    const float* w2c = (const float*)d_in[6];
    float* out = (float*)d_out;

    float* ws    = (float*)d_ws;
    float* pf    = ws + PF_OFF;
    float* pt    = ws + PT_OFF;
    float* pc    = ws + PC_OFF;
    float* gates = ws + G_OFF;
    int*   flag  = (int*)(ws + FL_OFF);

    pool_k<<<4096, 256, 0, stream>>>(x, pf, pt, pc, flag);
    gate_apply_k<<<24 + 1024, 512, 0, stream>>>(x, w1f, w2f, w1t, w2t,
                                                w1c, w2c, pf, pt, pc,
                                                gates, flag, out);
}

// Round 11
// 458.287 us; speedup vs baseline: 1.0336x; 1.0336x over previous
//
#include <hip/hip_runtime.h>
#include <math.h>

// Problem constants
#define BB 8
#define CC 64
#define TT 512
#define FF 256

typedef float floatx4 __attribute__((ext_vector_type(4)));

constexpr int TOFF = BB * FF;                       // 2048
constexpr int COFF = BB * FF + BB * TT;             // 6144
constexpr int NSUM = BB * FF + BB * TT + BB * CC;   // 6656 floats

// ws layout (floats)
constexpr long PF_OFF = 0;                          // Pfreq [4096][256]
constexpr long PT_OFF = PF_OFF + 4096L * 256;       // Ptime [4096][64]
constexpr long PC_OFF = PT_OFF + 4096L * 64;        // Pch   [4096]
constexpr long G_OFF  = PC_OFF + 4096;              // gates [NSUM]
constexpr long CN_OFF = G_OFF + NSUM;               // cnt   [8] ints

struct PoolShm { float tr[16][257]; float fr[256]; float cw[4]; }; // 17.5 KB
struct GateShm { float s[512]; float h[512]; };                    //  4 KB
union  Shm { PoolShm p; GateShm g; };

// ---------------------------------------------------------------------------
// Gate tail: run by the LAST pool block of each batch (8 winners, one per b —
// no spinning, no waiting; R8/R10 lesson: >8 pollers on one line = disaster).
// Computes all 3 gate units for batch b with 256 threads (R7-verified math).
// ---------------------------------------------------------------------------
__device__ __forceinline__ void gate_tail(
    const float* __restrict__ w1f, const float* __restrict__ w2f,
    const float* __restrict__ w1t, const float* __restrict__ w2t,
    const float* __restrict__ w1c, const float* __restrict__ w2c,
    const float* __restrict__ pf, const float* __restrict__ pt,
    const float* __restrict__ pc, float* __restrict__ gates,
    GateShm& gs, int b, int tid)
{
    // ---------- freq unit (dim 256) ----------
    {
        float a0 = 0.f, a1 = 0.f, a2 = 0.f, a3 = 0.f;
        const float* __restrict__ p = pf + (long)(b * 512) * 256 + tid;
        #pragma unroll 4
        for (int ch = 0; ch < 512; ch += 4) {
            a0 += p[(long)(ch + 0) * 256];
            a1 += p[(long)(ch + 1) * 256];
            a2 += p[(long)(ch + 2) * 256];
            a3 += p[(long)(ch + 3) * 256];
        }
        gs.s[tid] = ((a0 + a1) + (a2 + a3)) * (1.f / (float)(CC * TT));
    }
    __syncthreads();
    {
        const floatx4* __restrict__ wr = (const floatx4*)(w1f + (long)tid * FF);
        const floatx4* __restrict__ sv = (const floatx4*)gs.s;
        float c0 = 0.f, c1 = 0.f, c2 = 0.f, c3 = 0.f;
        for (int j = 0; j < FF / 4; ++j) {
            floatx4 w = wr[j], v = sv[j];
            c0 += w.x * v.x; c1 += w.y * v.y; c2 += w.z * v.z; c3 += w.w * v.w;
        }
        __syncthreads();
        gs.h[tid] = fmaxf((c0 + c1) + (c2 + c3), 0.f);
    }
    __syncthreads();
    {
        const floatx4* __restrict__ wr = (const floatx4*)(w2f + (long)tid * FF);
        const floatx4* __restrict__ hv = (const floatx4*)gs.h;
        float c0 = 0.f, c1 = 0.f, c2 = 0.f, c3 = 0.f;
        for (int j = 0; j < FF / 4; ++j) {
            floatx4 w = wr[j], v = hv[j];
            c0 += w.x * v.x; c1 += w.y * v.y; c2 += w.z * v.z; c3 += w.w * v.w;
        }
        gates[b * FF + tid] = 1.f / (1.f + expf(-((c0 + c1) + (c2 + c3))));
    }
    __syncthreads();

    // ---------- time unit (dim 512) ----------
    for (int t2 = tid; t2 < TT; t2 += 256) {
        float a0 = 0.f, a1 = 0.f, a2 = 0.f, a3 = 0.f;
        const float* __restrict__ p =
            pt + (long)(b * 512 + (t2 >> 6)) * 64 + (t2 & 63);
        #pragma unroll 4
        for (int c = 0; c < 64; c += 4) {
            a0 += p[(long)(c + 0) * 512];
            a1 += p[(long)(c + 1) * 512];
            a2 += p[(long)(c + 2) * 512];
            a3 += p[(long)(c + 3) * 512];
        }
        gs.s[t2] = ((a0 + a1) + (a2 + a3)) * (1.f / (float)(CC * FF));
    }
    __syncthreads();
    float hreg[2];
    #pragma unroll
    for (int r = 0; r < 2; ++r) {
        const int row = tid + r * 256;
        const floatx4* __restrict__ wr = (const floatx4*)(w1t + (long)row * TT);
        const floatx4* __restrict__ sv = (const floatx4*)gs.s;
        float c0 = 0.f, c1 = 0.f, c2 = 0.f, c3 = 0.f;
        for (int j = 0; j < TT / 4; ++j) {
            floatx4 w = wr[j], v = sv[j];
            c0 += w.x * v.x; c1 += w.y * v.y; c2 += w.z * v.z; c3 += w.w * v.w;
        }
        hreg[r] = fmaxf((c0 + c1) + (c2 + c3), 0.f);
    }
    __syncthreads();
    gs.h[tid] = hreg[0];
    gs.h[tid + 256] = hreg[1];
    __syncthreads();
    #pragma unroll
    for (int r = 0; r < 2; ++r) {
        const int row = tid + r * 256;
        const floatx4* __restrict__ wr = (const floatx4*)(w2t + (long)row * TT);
        const floatx4* __restrict__ hv = (const floatx4*)gs.h;
        float c0 = 0.f, c1 = 0.f, c2 = 0.f, c3 = 0.f;
        for (int j = 0; j < TT / 4; ++j) {
            floatx4 w = wr[j], v = hv[j];
            c0 += w.x * v.x; c1 += w.y * v.y; c2 += w.z * v.z; c3 += w.w * v.w;
        }
        gates[TOFF + b * TT + row] = 1.f / (1.f + expf(-((c0 + c1) + (c2 + c3))));
    }
    __syncthreads();

    // ---------- ch unit (dim 64) ----------
    if (tid < CC) {
        float acc = 0.f;
        #pragma unroll
        for (int j = 0; j < 8; ++j) acc += pc[b * 512 + tid * 8 + j];
        gs.s[tid] = acc * (1.f / (float)(TT * FF));
    }
    __syncthreads();
    if (tid < CC) {
        const floatx4* __restrict__ wr = (const floatx4*)(w1c + (long)tid * CC);
        const floatx4* __restrict__ sv = (const floatx4*)gs.s;
        float c0 = 0.f, c1 = 0.f, c2 = 0.f, c3 = 0.f;
        for (int j = 0; j < CC / 4; ++j) {
            floatx4 w = wr[j], v = sv[j];
            c0 += w.x * v.x; c1 += w.y * v.y; c2 += w.z * v.z; c3 += w.w * v.w;
        }
        __syncthreads();
        gs.h[tid] = fmaxf((c0 + c1) + (c2 + c3), 0.f);
    } else {
        __syncthreads();
    }
    __syncthreads();
    if (tid < CC) {
        const floatx4* __restrict__ wr = (const floatx4*)(w2c + (long)tid * CC);
        const floatx4* __restrict__ hv = (const floatx4*)gs.h;
        float c0 = 0.f, c1 = 0.f, c2 = 0.f, c3 = 0.f;
        for (int j = 0; j < CC / 4; ++j) {
            floatx4 w = wr[j], v = hv[j];
            c0 += w.x * v.x; c1 += w.y * v.y; c2 += w.z * v.z; c3 += w.w * v.w;
        }
        gates[COFF + b * CC + tid] = 1.f / (1.f + expf(-((c0 + c1) + (c2 + c3))));
    }
}

// ---------------------------------------------------------------------------
// Kernel 1: pool (R7-verified body) + per-batch last-block gate tail.
// One contiguous 64KB chunk per block; temporal loads fill L3 so apply's
// re-read hits L3 (R6: ~94%). After partial stores: release-fence +
// atomicAdd(&cnt[b]); the 512th arriver for batch b computes b's gates.
// ---------------------------------------------------------------------------
__global__ __launch_bounds__(256) void pool_gate_k(
    const float* __restrict__ x,
    const float* __restrict__ w1f, const float* __restrict__ w2f,
    const float* __restrict__ w1t, const float* __restrict__ w2t,
    const float* __restrict__ w1c, const float* __restrict__ w2c,
    float* __restrict__ pf, float* __restrict__ pt, float* __restrict__ pc,
    float* __restrict__ gates, int* __restrict__ cnt)
{
    __shared__ Shm u;
    __shared__ int win_s;
    const int tid  = threadIdx.x;
    const int lane = tid & 63;
    const int wid  = tid >> 6;
    const int chunk = blockIdx.x;                    // 0..4095
    const int b     = chunk >> 9;

    const floatx4* __restrict__ x4 = (const floatx4*)x;
    const long base = (long)chunk * 4096 + wid * 1024 + lane;

    float a0 = 0.f, a1 = 0.f, a2 = 0.f, a3 = 0.f;    // freq partials
    float ach[16];                                   // row sums (time)
    #pragma unroll
    for (int k = 0; k < 16; ++k) {
        floatx4 d = x4[base + k * 64];               // temporal: fill L3
        a0 += d.x; a1 += d.y; a2 += d.z; a3 += d.w;
        ach[k] = (d.x + d.y) + (d.z + d.w);
    }
    float csum = 0.f;
    #pragma unroll
    for (int k = 0; k < 16; ++k) csum += ach[k];
    #pragma unroll
    for (int o = 32; o > 0; o >>= 1) csum += __shfl_xor(csum, o, 64);

    u.p.fr[tid] = 0.f;
    #pragma unroll
    for (int k = 0; k < 16; ++k) u.p.tr[k][tid] = ach[k];
    if (lane == 0) u.p.cw[wid] = csum;
    __syncthreads();

    atomicAdd(&u.p.fr[4 * lane + 0], a0);
    atomicAdd(&u.p.fr[4 * lane + 1], a1);
    atomicAdd(&u.p.fr[4 * lane + 2], a2);
    atomicAdd(&u.p.fr[4 * lane + 3], a3);

    {   // time: row s of chunk summed by 4 threads (q), then 2 shuffles
        const int s = tid >> 2, q = tid & 3;
        float v = 0.f;
        #pragma unroll
        for (int j = 0; j < 16; ++j)
            v += u.p.tr[s & 15][(s >> 4) * 64 + q * 16 + j];
        v += __shfl_xor(v, 1, 64);
        v += __shfl_xor(v, 2, 64);
        if (q == 0) pt[chunk * 64 + s] = v;
    }
    __syncthreads();

    pf[chunk * 256 + tid] = u.p.fr[tid];
    if (tid == 0) pc[chunk] = (u.p.cw[0] + u.p.cw[1]) + (u.p.cw[2] + u.p.cw[3]);

    // ---- last-block-per-batch election (no waiting, no polling) ----
    __syncthreads();                       // partial stores issued block-wide
    if (tid == 0) {
        __threadfence();                   // release: publish our partials
        win_s = (atomicAdd(&cnt[b], 1) == 511);
    }
    __syncthreads();
    if (win_s) {
        __threadfence();                   // acquire: see all b's partials
        gate_tail(w1f, w2f, w1t, w2t, w1c, w2c, pf, pt, pc, gates, u.g,
                  b, tid);
    }
}

// ---------------------------------------------------------------------------
// Kernel 2: apply (R7-verified). Descending order chases pool's MRU L3
// content ahead of out-write evictions (R6: ~94% L3 hits); nt stores keep
// out from evicting x.
// ---------------------------------------------------------------------------
__global__ __launch_bounds__(256) void apply_k(const float* __restrict__ x,
                                               const float* __restrict__ gts,
                                               float* __restrict__ out) {
    const floatx4* __restrict__ x4 = (const floatx4*)x;
    floatx4* __restrict__ o4 = (floatx4*)out;
    const long base3 = (long)blockIdx.x * 256 + threadIdx.x;   // < 2^19
    const int f4 = (int)(base3 & 63);
    const int t  = (int)((base3 >> 6) & (TT - 1));
    const int cb = (int)((base3 >> 15) & (CC - 1));
    #pragma unroll 8
    for (int k = 31; k >= 0; --k) {
        const int b = k >> 2;
        const int c = (cb + k * 16) & (CC - 1);
        const floatx4 fm = ((const floatx4*)(gts + b * FF))[f4];
        const float gadd = gts[TOFF + b * TT + t]
                         + gts[COFF + b * CC + c] + 1.0f;
        const long v = base3 + ((long)k << 19);
        floatx4 d = x4[v];                           // mostly L3 hits
        floatx4 o = d * (fm + gadd);
        __builtin_nontemporal_store(o, &o4[v]);
    }
}

__global__ void zero_cnt_k(int* __restrict__ cnt) {
    if (threadIdx.x < 8) cnt[threadIdx.x] = 0;
}

extern "C" void kernel_launch(void* const* d_in, const int* in_sizes, int n_in,
                              void* d_out, int out_size, void* d_ws, size_t ws_size,
                              hipStream_t stream) {
    const float* x   = (const float*)d_in[0];
    const float* w1f = (const float*)d_in[1];
    const float* w2f = (const float*)d_in[2];
    const float* w1t = (const float*)d_in[3];
    const float* w2t = (const float*)d_in[4];
    const float* w1c = (const float*)d_in[5];
    const float* w2c = (const float*)d_in[6];
    float* out = (float*)d_out;

    float* ws    = (float*)d_ws;
    float* pf    = ws + PF_OFF;
    float* pt    = ws + PT_OFF;
    float* pc    = ws + PC_OFF;
    float* gates = ws + G_OFF;
    int*   cnt   = (int*)(ws + CN_OFF);

    zero_cnt_k<<<1, 64, 0, stream>>>(cnt);
    pool_gate_k<<<4096, 256, 0, stream>>>(x, w1f, w2f, w1t, w2t, w1c, w2c,
                                          pf, pt, pc, gates, cnt);
    apply_k<<<2048, 256, 0, stream>>>(x, gates, out);
}

// Round 12
// 211.215 us; speedup vs baseline: 2.2426x; 2.1698x over previous
//
#include <hip/hip_runtime.h>
#include <math.h>

// Problem constants
#define BB 8
#define CC 64
#define TT 512
#define FF 256

typedef float floatx4 __attribute__((ext_vector_type(4)));

constexpr int TOFF = BB * FF;                       // 2048
constexpr int COFF = BB * FF + BB * TT;             // 6144
constexpr int NSUM = BB * FF + BB * TT + BB * CC;   // 6656 floats

// ws layout (floats)
constexpr long PF_OFF = 0;                          // Pfreq [4096][256]
constexpr long PT_OFF = PF_OFF + 4096L * 256;       // Ptime [4096][64]
constexpr long PC_OFF = PT_OFF + 4096L * 64;        // Pch   [4096]
constexpr long G_OFF  = PC_OFF + 4096;              // gates [NSUM]

// ---------------------------------------------------------------------------
// Kernel 1: pool — BYTE-IDENTICAL logic to R7 (the 204us baseline component).
// One contiguous 64KB chunk per block, register-only inner loop, one-time
// cross-lane epilogue, plain-store partials (no atomics, no zeroing).
// Temporal loads keep x resident in L3: R6 showed apply then fetches only
// ~16MB from HBM; R11 showed even pool starts half-L3-fed across replays.
// NO device-scope fences anywhere (R11 lesson: 4096 fences = +340us).
// ---------------------------------------------------------------------------
__global__ __launch_bounds__(256) void pool_k(const float* __restrict__ x,
                                              float* __restrict__ pf,
                                              float* __restrict__ pt,
                                              float* __restrict__ pc) {
    __shared__ float tr[16][257];
    __shared__ float fr[256];
    __shared__ float cw[4];
    const int tid  = threadIdx.x;
    const int lane = tid & 63;
    const int wid  = tid >> 6;
    const int chunk = blockIdx.x;                    // 0..4095

    const floatx4* __restrict__ x4 = (const floatx4*)x;
    const long base = (long)chunk * 4096 + wid * 1024 + lane;

    float a0 = 0.f, a1 = 0.f, a2 = 0.f, a3 = 0.f;    // freq partials
    float ach[16];                                   // row sums (time)
    #pragma unroll
    for (int k = 0; k < 16; ++k) {
        floatx4 d = x4[base + k * 64];               // temporal: fill L3
        a0 += d.x; a1 += d.y; a2 += d.z; a3 += d.w;
        ach[k] = (d.x + d.y) + (d.z + d.w);
    }
    float csum = 0.f;
    #pragma unroll
    for (int k = 0; k < 16; ++k) csum += ach[k];
    #pragma unroll
    for (int o = 32; o > 0; o >>= 1) csum += __shfl_xor(csum, o, 64);

    fr[tid] = 0.f;
    #pragma unroll
    for (int k = 0; k < 16; ++k) tr[k][tid] = ach[k];
    if (lane == 0) cw[wid] = csum;
    __syncthreads();

    atomicAdd(&fr[4 * lane + 0], a0);
    atomicAdd(&fr[4 * lane + 1], a1);
    atomicAdd(&fr[4 * lane + 2], a2);
    atomicAdd(&fr[4 * lane + 3], a3);

    {   // time: row s of chunk summed by 4 threads (q), then 2 shuffles
        const int s = tid >> 2, q = tid & 3;
        float v = 0.f;
        #pragma unroll
        for (int j = 0; j < 16; ++j)
            v += tr[s & 15][(s >> 4) * 64 + q * 16 + j];
        v += __shfl_xor(v, 1, 64);
        v += __shfl_xor(v, 2, 64);
        if (q == 0) pt[chunk * 64 + s] = v;
    }
    __syncthreads();

    pf[chunk * 256 + tid] = fr[tid];
    if (tid == 0) pc[chunk] = (cw[0] + cw[1]) + (cw[2] + cw[3]);
}

// ---------------------------------------------------------------------------
// Kernel 2: gate. 24 blocks x 512 threads (one (g,b) unit per block; unit
// cost is capped by weights-through-one-CU, T-unit = 2MB -> ~13us floor).
// This round: deeper load pipelining on the partial reductions (8 accs,
// unroll 16 -> 8+ independent loads in flight vs 4) and nt partial loads
// (single-use data), unroll 4 on every matmul dot loop.
// ---------------------------------------------------------------------------
__global__ __launch_bounds__(512) void gate_k(
    const float* __restrict__ w1f, const float* __restrict__ w2f,
    const float* __restrict__ w1t, const float* __restrict__ w2t,
    const float* __restrict__ w1c, const float* __restrict__ w2c,
    const float* __restrict__ pf, const float* __restrict__ pt,
    const float* __restrict__ pc, float* __restrict__ gates) {
    __shared__ __align__(16) float s[512];
    __shared__ __align__(16) float h[512];
    const int g = blockIdx.x >> 3;
    const int b = blockIdx.x & 7;
    const int tid = threadIdx.x;

    int dim; const float *w1, *w2; float* gout; float inv;
    if (g == 0) { dim = FF; w1 = w1f; w2 = w2f; gout = gates + b * FF;
                  inv = 1.f / (float)(CC * TT); }
    else if (g == 1) { dim = TT; w1 = w1t; w2 = w2t; gout = gates + TOFF + b * TT;
                  inv = 1.f / (float)(CC * FF); }
    else { dim = CC; w1 = w1c; w2 = w2c; gout = gates + COFF + b * CC;
                  inv = 1.f / (float)(TT * FF); }

    // ---- reduce partials into s[0..dim) ----
    if (g == 0) {
        // thread (f = tid&255, half = tid>>8) sums 256 chunks, 8 accumulators
        const int f = tid & 255, half = tid >> 8;
        const float* __restrict__ p =
            pf + ((long)(b * 512 + half * 256) * 256) + f;
        float a[8];
        #pragma unroll
        for (int i = 0; i < 8; ++i) a[i] = 0.f;
        #pragma unroll 2
        for (int ch = 0; ch < 256; ch += 8) {
            #pragma unroll
            for (int i = 0; i < 8; ++i)
                a[i] += __builtin_nontemporal_load(&p[(long)(ch + i) * 256]);
        }
        h[tid] = ((a[0] + a[1]) + (a[2] + a[3]))
               + ((a[4] + a[5]) + (a[6] + a[7]));
        __syncthreads();
        if (tid < 256) s[tid] = (h[tid] + h[tid + 256]) * inv;
    } else if (g == 1) {
        // thread t sums 64 chunk-partials (stride 512 floats), 4 accumulators
        const float* __restrict__ p =
            pt + ((long)(b * 512 + (tid >> 6)) * 64) + (tid & 63);
        float a0 = 0.f, a1 = 0.f, a2 = 0.f, a3 = 0.f;
        #pragma unroll 4
        for (int c = 0; c < 64; c += 4) {
            a0 += __builtin_nontemporal_load(&p[(long)(c + 0) * 512]);
            a1 += __builtin_nontemporal_load(&p[(long)(c + 1) * 512]);
            a2 += __builtin_nontemporal_load(&p[(long)(c + 2) * 512]);
            a3 += __builtin_nontemporal_load(&p[(long)(c + 3) * 512]);
        }
        s[tid] = ((a0 + a1) + (a2 + a3)) * inv;
    } else {
        if (tid < CC) {
            float acc = 0.f;
            #pragma unroll
            for (int j = 0; j < 8; ++j)
                acc += __builtin_nontemporal_load(&pc[b * 512 + tid * 8 + j]);
            s[tid] = acc * inv;
        }
    }
    __syncthreads();

    // ---- layer 1: relu(s @ W1^T) ----
    for (int row = tid; row < dim; row += 512) {
        const floatx4* __restrict__ wr = (const floatx4*)(w1 + (long)row * dim);
        const floatx4* __restrict__ sv = (const floatx4*)s;
        float c0 = 0.f, c1 = 0.f, c2 = 0.f, c3 = 0.f;
        #pragma unroll 4
        for (int j = 0; j < dim / 4; ++j) {
            floatx4 w = wr[j]; floatx4 sj = sv[j];
            c0 += w.x * sj.x; c1 += w.y * sj.y; c2 += w.z * sj.z; c3 += w.w * sj.w;
        }
        h[row] = fmaxf((c0 + c1) + (c2 + c3), 0.f);
    }
    __syncthreads();
    // ---- layer 2: sigmoid(h @ W2^T) ----
    for (int row = tid; row < dim; row += 512) {
        const floatx4* __restrict__ wr = (const floatx4*)(w2 + (long)row * dim);
        const floatx4* __restrict__ hv = (const floatx4*)h;
        float c0 = 0.f, c1 = 0.f, c2 = 0.f, c3 = 0.f;
        #pragma unroll 4
        for (int j = 0; j < dim / 4; ++j) {
            floatx4 w = wr[j]; floatx4 hj = hv[j];
            c0 += w.x * hj.x; c1 += w.y * hj.y; c2 += w.z * hj.z; c3 += w.w * hj.w;
        }
        gout[row] = 1.f / (1.f + expf(-((c0 + c1) + (c2 + c3))));
    }
}

// ---------------------------------------------------------------------------
// Kernel 3: apply, b-outer / j-inner with per-b hoisted gate loads
// (R7 reloaded fm every k: 32 vector + 64 scalar loads/thread -> now 8+16).
// Descending (b,j) chases pool's MRU L3 content (R6: ~94% L3 hits);
// nt-store keeps out from evicting x.  v = base3 + k*2^19, k = b*4+j.
// ---------------------------------------------------------------------------
__global__ __launch_bounds__(256) void apply_k(const float* __restrict__ x,
                                               const float* __restrict__ gts,
                                               float* __restrict__ out) {
    const floatx4* __restrict__ x4 = (const floatx4*)x;
    floatx4* __restrict__ o4 = (floatx4*)out;
    const long base3 = (long)blockIdx.x * 256 + threadIdx.x;   // < 2^19
    const int f4 = (int)(base3 & 63);
    const int t  = (int)((base3 >> 6) & (TT - 1));
    const int cb = (int)((base3 >> 15) & (CC - 1));
    #pragma unroll 2
    for (int b = 7; b >= 0; --b) {
        const floatx4 fm = ((const floatx4*)(gts + b * FF))[f4];
        const float tm1 = gts[TOFF + b * TT + t] + 1.0f;
        #pragma unroll
        for (int j = 3; j >= 0; --j) {
            const int k = b * 4 + j;
            const int c = (cb + k * 16) & (CC - 1);
            const float gadd = tm1 + gts[COFF + b * CC + c];
            const long v = base3 + ((long)k << 19);
            floatx4 d = x4[v];                       // mostly L3 hits
            floatx4 o = d * (fm + gadd);
            __builtin_nontemporal_store(o, &o4[v]);
        }
    }
}

extern "C" void kernel_launch(void* const* d_in, const int* in_sizes, int n_in,
                              void* d_out, int out_size, void* d_ws, size_t ws_size,
                              hipStream_t stream) {
    const float* x   = (const float*)d_in[0];
    const float* w1f = (const float*)d_in[1];
    const float* w2f = (const float*)d_in[2];
    const float* w1t = (const float*)d_in[3];
    const float* w2t = (const float*)d_in[4];
    const float* w1c = (const float*)d_in[5];
    const float* w2c = (const float*)d_in[6];
    float* out = (float*)d_out;

    float* ws    = (float*)d_ws;
    float* pf    = ws + PF_OFF;
    float* pt    = ws + PT_OFF;
    float* pc    = ws + PC_OFF;
    float* gates = ws + G_OFF;

    pool_k<<<4096, 256, 0, stream>>>(x, pf, pt, pc);
    gate_k<<<24, 512, 0, stream>>>(w1f, w2f, w1t, w2t, w1c, w2c,
                                   pf, pt, pc, gates);
    apply_k<<<2048, 256, 0, stream>>>(x, gates, out);
}